// Round 5
// baseline (158.515 us; speedup 1.0000x reference)
//
#include <hip/hip_runtime.h>

// LIF neuron forward: V = leak*V + I; spike = (V >= 1); V -= spike.
// current: [B=8, S=4096, D=1024] f32, membrane: [B, D] f32.
// Outputs concatenated: spikes [B,S,D] then mem_final [B,D], all f32.
//
// Forward spike value == hard threshold exactly (the surrogate-sigmoid
// straight-through trick is an exact no-op in fp32 — see Sterbenz argument),
// so we skip expf entirely. fp contraction is disabled so LEAK*mem + cur
// rounds mul-then-add, matching a numpy float32 replay bit-exactly.

#define LIF_B 8
#define LIF_S 4096
#define LIF_D 1024
#define LIF_U 32  // prefetch depth (registers per buffer)

__global__ __launch_bounds__(64, 1) void lif_fwd_kernel(
    const float* __restrict__ current,
    const float* __restrict__ membrane,
    float* __restrict__ spikes,
    float* __restrict__ mem_out)
{
    #pragma clang fp contract(off)

    const int idx = blockIdx.x * blockDim.x + threadIdx.x;  // 0..8191
    if (idx >= LIF_B * LIF_D) return;
    const int b = idx >> 10;          // / LIF_D
    const int d = idx & (LIF_D - 1);  // % LIF_D

    const float* cur  = current + (size_t)b * LIF_S * LIF_D + d;
    float*       outp = spikes  + (size_t)b * LIF_S * LIF_D + d;

    float mem = membrane[idx];

    float buf0[LIF_U], buf1[LIF_U];

    // prologue: fetch chunk 0
    #pragma unroll
    for (int u = 0; u < LIF_U; ++u)
        buf0[u] = cur[(size_t)u * LIF_D];

    for (int t0 = 0; t0 < LIF_S; t0 += 2 * LIF_U) {
        // prefetch chunk t0+U while computing chunk t0
        #pragma unroll
        for (int u = 0; u < LIF_U; ++u)
            buf1[u] = cur[(size_t)(t0 + LIF_U + u) * LIF_D];

        #pragma unroll
        for (int u = 0; u < LIF_U; ++u) {
            mem = 0.9f * mem + buf0[u];              // mul-then-add (no FMA)
            const float spike = (mem >= 1.0f) ? 1.0f : 0.0f;
            outp[(size_t)(t0 + u) * LIF_D] = spike;
            mem -= spike;                            // soft reset (theta = 1)
        }

        // prefetch chunk t0+2U while computing chunk t0+U
        if (t0 + 2 * LIF_U < LIF_S) {
            #pragma unroll
            for (int u = 0; u < LIF_U; ++u)
                buf0[u] = cur[(size_t)(t0 + 2 * LIF_U + u) * LIF_D];
        }

        #pragma unroll
        for (int u = 0; u < LIF_U; ++u) {
            mem = 0.9f * mem + buf1[u];
            const float spike = (mem >= 1.0f) ? 1.0f : 0.0f;
            outp[(size_t)(t0 + LIF_U + u) * LIF_D] = spike;
            mem -= spike;
        }
    }

    mem_out[idx] = mem;
}

extern "C" void kernel_launch(void* const* d_in, const int* in_sizes, int n_in,
                              void* d_out, int out_size, void* d_ws, size_t ws_size,
                              hipStream_t stream) {
    const float* current  = (const float*)d_in[0];   // [8, 4096, 1024]
    const float* membrane = (const float*)d_in[1];   // [8, 1024]

    float* spikes  = (float*)d_out;                               // [8,4096,1024]
    float* mem_out = (float*)d_out + (size_t)LIF_B * LIF_S * LIF_D; // [8,1024]

    const int total = LIF_B * LIF_D;     // 8192 chains
    dim3 block(64);
    dim3 grid(total / 64);               // 128 blocks -> 128 CUs, 1 wave each

    hipLaunchKernelGGL(lif_fwd_kernel, grid, block, 0, stream,
                       current, membrane, spikes, mem_out);
}

// Round 6
// 117.222 us; speedup vs baseline: 1.3523x; 1.3523x over previous
//
#include <hip/hip_runtime.h>

// LIF neuron forward, producer-consumer wave specialization.
// V = leak*V + I; spike = (V >= 1); V -= spike.
// current: [B=8, S=4096, D=1024] f32, membrane: [B, D] f32.
// Outputs concatenated: spikes [B,S,D] then mem_final [B,D], all f32.
//
// Round-5 evidence: register prefetch collapses (VGPR_Count=64 -> compiler
// refused the 32-deep pipeline), 158 us latency-bound at ~1 TB/s. Fix:
// wave 0 = consumer (serial chain, 64 channels, one/lane); waves 1-3 =
// producers streaming rows into a double-buffered LDS ring via
// global_load_lds (no VGPR destination -> queue depth is hardware vmcnt,
// not register allocation). LDS dest is wave-uniform base + lane*4, which
// matches ring[buf][r][0..63] exactly (lane i == channel i, contiguous).
//
// Numerics (validated round 5, absmax 7.6e-6): forward spike == hard
// threshold exactly in fp32; fp contract(off) pins mul-then-add rounding.

#define LIF_B 8
#define LIF_S 4096
#define LIF_D 1024
#define CHUNK 128                    // time steps per ring half
#define NHALF (LIF_S / CHUNK)        // 32

__global__ __launch_bounds__(256, 1) void lif_pc_kernel(
    const float* __restrict__ current,
    const float* __restrict__ membrane,
    float* __restrict__ spikes,
    float* __restrict__ mem_out)
{
    #pragma clang fp contract(off)

    __shared__ float ring[2][CHUNK][64];   // 64 KB double buffer

    const int wid  = threadIdx.x >> 6;     // 0 = consumer, 1..3 = producers
    const int lane = threadIdx.x & 63;
    const int blk  = blockIdx.x;           // 0..127
    const int bb   = blk >> 4;             // batch index (1024/64 = 16 ch-blocks)
    const int ch0  = (blk & 15) * 64;      // first channel of this block

    // per-lane global source: current[bb][t][ch0 + lane]
    const float* curbase = current + (size_t)bb * LIF_S * LIF_D + ch0 + lane;

    float mem = 0.0f;
    const int mi = bb * LIF_D + ch0 + lane;
    float* outp = spikes + (size_t)bb * LIF_S * LIF_D + ch0 + lane;

    // ---- prologue: producers fill half 0; consumer loads membrane ----
    if (wid != 0) {
        const int p = wid - 1;  // 0..2
        for (int r = p; r < CHUNK; r += 3) {
            auto* ldst = (__attribute__((address_space(3))) unsigned int*)
                         (void*)&ring[0][r][0];
            __builtin_amdgcn_global_load_lds(
                (const __attribute__((address_space(1))) unsigned int*)
                    (const void*)(curbase + (size_t)r * LIF_D),
                ldst, 4, 0, 0);
        }
    } else {
        mem = membrane[mi];
    }
    __syncthreads();   // drains producers' vmcnt -> half 0 resident

    // ---- main loop: consumer eats half h, producers fill half h+1 ----
    for (int h = 0; h < NHALF; ++h) {
        if (wid != 0) {
            if (h + 1 < NHALF) {
                const int p     = wid - 1;
                const int buf   = (h + 1) & 1;
                const int tbase = (h + 1) * CHUNK;
                for (int r = p; r < CHUNK; r += 3) {
                    auto* ldst = (__attribute__((address_space(3))) unsigned int*)
                                 (void*)&ring[buf][r][0];
                    __builtin_amdgcn_global_load_lds(
                        (const __attribute__((address_space(1))) unsigned int*)
                            (const void*)(curbase + (size_t)(tbase + r) * LIF_D),
                        ldst, 4, 0, 0);
                }
            }
        } else {
            const int buf   = h & 1;
            const int tbase = h * CHUNK;
            #pragma unroll 8
            for (int r = 0; r < CHUNK; ++r) {
                const float c     = ring[buf][r][lane];       // ds_read_b32, conflict-free
                const float v     = 0.9f * mem + c;           // mul-then-add (no FMA)
                const float spike = (v >= 1.0f) ? 1.0f : 0.0f;
                outp[(size_t)(tbase + r) * LIF_D] = spike;
                mem = v - spike;                              // soft reset (theta = 1)
            }
        }
        __syncthreads();
    }

    if (wid == 0) mem_out[mi] = mem;
}

extern "C" void kernel_launch(void* const* d_in, const int* in_sizes, int n_in,
                              void* d_out, int out_size, void* d_ws, size_t ws_size,
                              hipStream_t stream) {
    const float* current  = (const float*)d_in[0];   // [8, 4096, 1024]
    const float* membrane = (const float*)d_in[1];   // [8, 1024]

    float* spikes  = (float*)d_out;                                 // [8,4096,1024]
    float* mem_out = (float*)d_out + (size_t)LIF_B * LIF_S * LIF_D; // [8,1024]

    dim3 block(256);                     // 4 waves: 1 consumer + 3 producers
    dim3 grid(LIF_B * LIF_D / 64);       // 128 blocks (64 channels each)

    hipLaunchKernelGGL(lif_pc_kernel, grid, block, 0, stream,
                       current, membrane, spikes, mem_out);
}